// Round 4
// baseline (352.194 us; speedup 1.0000x reference)
//
#include <hip/hip_runtime.h>
#include <hip/hip_bf16.h>

typedef short v8s __attribute__((ext_vector_type(8)));
typedef float v4f __attribute__((ext_vector_type(4)));
typedef float v16f __attribute__((ext_vector_type(16)));
typedef unsigned short u16;

#define PROW 58
#define PCOL 64

// ws layout (octet-major, conflict-free ds_read_b128):
//   A:  [cc 8][n 32][row 58][q 4][col 64][j 8] bf16   (ch = q*8+j within cc)
//   Wb: [kk 9][cc 8][ocb 2][q 4][ocl 128][j 8] bf16   (ic = cc*32+q*8+j, oc = ocb*128+ocl)
static constexpr size_t A_CC_STRIDE = (size_t)32 * PROW * PCOL * 32;   // elems
static constexpr size_t A_BYTES     = 8 * A_CC_STRIDE * 2;
static constexpr size_t WB_ELEMS    = (size_t)9 * 8 * 256 * 32;

__device__ __forceinline__ void gl2lds16(const void* gptr, void* lptr) {
  auto g = (const __attribute__((address_space(1))) unsigned int*)gptr;
  auto l = (__attribute__((address_space(3))) unsigned int*)lptr;
  __builtin_amdgcn_global_load_lds(g, l, 16, 0, 0);
}

__device__ __forceinline__ u16 f2bf(float f) {
  __hip_bfloat16 h = __float2bfloat16(f);
  union { __hip_bfloat16 b; u16 u; } cv; cv.b = h; return cv.u;
}

// ---------------------------------------------------------------------------
// Hg table: B[c,c'] = golay(c) * (-1)^popc(c&c'), entries +-1 exact in bf16,
// stored pre-swizzled in 32x32x16 MFMA B-fragment order:
//   [ks 16][ntile 8][lane 64][j 8],
//   element (lane,j) = B[ ks*16 + (lane>>5)*8 + j ][ nt*32 + (lane&31) ]
// 128 KB .rodata, L2-resident.
// ---------------------------------------------------------------------------
struct alignas(16) HgTab {
  u16 v[16 * 8 * 64 * 8];
  constexpr HgTab() : v{} {
    for (int ks = 0; ks < 16; ks++)
      for (int nt = 0; nt < 8; nt++)
        for (int l = 0; l < 64; l++)
          for (int j = 0; j < 8; j++) {
            int c  = ks * 16 + ((l >> 5) << 3) + j;
            int cp = (nt << 5) + (l & 31);
            int s  = (__builtin_popcount((unsigned)(c & cp)) +
                      __builtin_popcount((unsigned)(c & (c >> 1)))) & 1;
            v[(((ks << 3) + nt) << 9) + (l << 3) + j] = (u16)(s ? 0xBF80 : 0x3F80);
          }
  }
};
static_assert(sizeof(HgTab) == 131072, "HgTab size");
__device__ const HgTab HG{};

// ---------------- kernel 1: golay * FWHT * RMSNorm via MFMA ----------------
// Per block (n, y): Y[56,256] = X[56,256] @ B[256,256] with hi/lo bf16 split.
// Per-wave-private double-buffered DMA staging (global_load_lds), barrier-free
// counted-vmcnt pipeline. No __syncthreads in the loop.
__global__ __launch_bounds__(256, 4) void fwht_kernel(
    const float* __restrict__ x, const float* __restrict__ rms_w,
    u16* __restrict__ A)
{
  __shared__ __align__(16) float xs[4][2][16][64];   // per-wave double buffer, 32 KB
  __shared__ float ssbuf[2][64];                     // [n-half][pos] partial SS

  const int tid = threadIdx.x;
  const int y = blockIdx.x;
  const int n = blockIdx.y;

  const int lane = tid & 63;
  const int wv   = tid >> 6;
  const int mt   = wv & 1;     // M-tile: positions mt*32..mt*32+31
  const int nh   = wv >> 1;    // N-half: c' in [nh*128, nh*128+128)
  const int l31  = lane & 31;
  const int h    = lane >> 5;  // k-octet selector

  const int pos  = mt * 32 + l31;
  const int posl = pos > 55 ? 55 : pos;          // rows 56..63 are dead (never stored)

  // staging geometry: lane covers 16 B at slice offset lane*16;
  // row = 4*chunk + (lane>>4), col = (lane&15)*4 (clamped: cols 56..63 dup 52..55)
  const float* xrow = x + (size_t)n * 802816 + (size_t)y * 56;
  const int rr = lane >> 4;
  int c4 = (lane & 15) * 4; if (c4 > 52) c4 = 52;

  float* db0 = &xs[wv][0][0][0];
  float* db1 = &xs[wv][1][0][0];

  auto stage = [&](int ks, float* db) {
    const float* sb = xrow + (size_t)(ks * 16 + rr) * 3136 + c4;
    #pragma unroll
    for (int k = 0; k < 4; k++)
      gl2lds16(sb + (size_t)(k * 4) * 3136, db + k * 256 + lane * 4);
  };

  v16f acc[4];
  #pragma unroll
  for (int nt = 0; nt < 4; nt++)
    #pragma unroll
    for (int e = 0; e < 16; e++)
      acc[nt][e] = 0.0f;

  stage(0, db0);

  #pragma unroll
  for (int ks = 0; ks < 16; ks++) {
    float* cb = (ks & 1) ? db1 : db0;
    float* nb = (ks & 1) ? db0 : db1;

    // B-fragment loads first: older than the prefetch DMAs in the vmcnt FIFO
    v8s bfr[4];
    #pragma unroll
    for (int nt = 0; nt < 4; nt++)
      bfr[nt] = *(const v8s*)(HG.v + ((size_t)(((ks * 8) + nh * 4 + nt) * 64 + lane)) * 8);
    __builtin_amdgcn_sched_barrier(0);

    if (ks < 15) stage(ks + 1, nb);
    __builtin_amdgcn_sched_barrier(0);

    // drain: current-slice DMAs + this step's B loads; keep 4 new DMAs in flight
    asm volatile("s_waitcnt vmcnt(4)" ::: "memory");
    __builtin_amdgcn_sched_barrier(0);

    v8s ah, al;
    #pragma unroll
    for (int j = 0; j < 8; j++) {
      float v = cb[(h * 8 + j) * 64 + posl];       // 32 consecutive lanes, conflict-free
      unsigned u  = __float_as_uint(v);
      unsigned hu = u & 0xFFFF0000u;               // truncated-bf16 hi (exact residual)
      float r = v - __uint_as_float(hu);
      ah[j] = (short)(hu >> 16);
      al[j] = (short)f2bf(r);
    }
    #pragma unroll
    for (int nt = 0; nt < 4; nt++) {
      acc[nt] = __builtin_amdgcn_mfma_f32_32x32x16_bf16(ah, bfr[nt], acc[nt], 0, 0, 0);
      acc[nt] = __builtin_amdgcn_mfma_f32_32x32x16_bf16(al, bfr[nt], acc[nt], 0, 0, 0);
    }
  }

  // row sum-of-squares: C/D layout col=lane&31 (=c'), row=(g&3)+8*(g>>2)+4*h
  #pragma unroll
  for (int g = 0; g < 16; g++) {
    float s = acc[0][g] * acc[0][g] + acc[1][g] * acc[1][g]
            + acc[2][g] * acc[2][g] + acc[3][g] * acc[3][g];
    #pragma unroll
    for (int m = 1; m <= 16; m <<= 1) s += __shfl_xor(s, m, 64);  // within 32-half
    if (l31 == 0)
      ssbuf[nh][mt * 32 + (g & 3) + 8 * (g >> 2) + 4 * h] = s;
  }
  __syncthreads();

  float rwv[4];
  #pragma unroll
  for (int nt = 0; nt < 4; nt++)
    rwv[nt] = rms_w[nh * 128 + nt * 32 + l31];

  const int jj  = lane & 7;   // j within octet
  const int icq = l31 >> 3;   // ch octet q

  #pragma unroll
  for (int g = 0; g < 16; g++) {
    const int rg   = (g & 3) + 8 * (g >> 2) + 4 * h;
    const int posg = mt * 32 + rg;
    float ssum = ssbuf[0][posg] + ssbuf[1][posg];
    float sc = rsqrtf(ssum * (1.0f / 256.0f) + 1e-5f);
    if (posg < 56) {
      const int col = posg + 1;
      const size_t rowoff = ((size_t)icq * 64 + col) * 8 + jj;   // octet-major
      #pragma unroll
      for (int nt = 0; nt < 4; nt++) {
        const int cc = nh * 4 + nt;                 // c' = cc*32 + l31
        size_t go = (((size_t)cc * 32 + n) * PROW + (y + 1)) * 2048 + rowoff;
        A[go] = f2bf(acc[nt][g] * sc * rwv[nt]);
      }
    }
  }

  // halo cols 0 and 57..63 of this row (all 4 q-octets)
  {
    const v8s z = {0,0,0,0,0,0,0,0};
    int cc = tid >> 5;
    int s  = tid & 31;
    int q  = s >> 3, cidx = s & 7;
    int col = (cidx == 0) ? 0 : (56 + cidx);       // {0,57,...,63}
    size_t rb = (((size_t)cc * 32 + n) * PROW + (y + 1)) * 2048;
    *(v8s*)(A + rb + ((size_t)q * 64 + col) * 8) = z;
  }
  // halo rows 0 / 57 (full rows, layout-agnostic)
  if (y == 0 || y == 55) {
    const v8s z = {0,0,0,0,0,0,0,0};
    const int r = (y == 0) ? 0 : 57;
    #pragma unroll
    for (int i = 0; i < 8; i++) {
      int c = tid + 256 * i;             // 2048 chunks
      int cc = c >> 8, rem = c & 255;
      size_t go = (((size_t)cc * 32 + n) * PROW + r) * 2048 + rem * 8;
      *(v8s*)(A + go) = z;
    }
  }
}

// ---------------- kernel 2: W fp32 -> swizzled bf16 (octet-major) ----------------
__global__ __launch_bounds__(256) void wconv_kernel(
    const float* __restrict__ Wf, u16* __restrict__ Wb)
{
  int t = blockIdx.x * 256 + threadIdx.x;
  int kk = t >> 16;
  int cc = (t >> 13) & 7;
  int r  = t & 8191;
  int ocb = r >> 12;
  int q   = (r >> 10) & 3;
  int ocl = (r >> 3) & 127;
  int j   = r & 7;
  int oc = ocb * 128 + ocl;
  int ic = cc * 32 + q * 8 + j;
  int ky = kk / 3, kx = kk - ky * 3;
  float w = Wf[((oc * 256 + ic) * 3 + ky) * 3 + kx];
  Wb[t] = f2bf(w);
}

// ---------------- kernel 3: implicit-GEMM conv, 32x32x16 MFMA, 3-tap B staging ----------------
// LDS = 40960 B exactly; 4 blocks/CU fills the 160 KB pool exactly.
// Octet-major As/Bs: fragment ds_read_b128 are sequential 16-B slots -> conflict-free.
__global__ __launch_bounds__(256, 4) void conv_kernel(
    const u16* __restrict__ A, const u16* __restrict__ Wb,
    const float* __restrict__ bias, float* __restrict__ out)
{
  __shared__ __align__(16) u16 As[4 * 2048];          // 16 KB: 4 rows [q4][col64][j8]
  __shared__ __align__(16) u16 Bs[3 * 4096];          // 24 KB: 3 taps [q4][ocl128][j8]

  const int tid  = threadIdx.x;
  const int lane = tid & 63;
  const int wv   = tid >> 6;
  const int wm   = wv & 1;          // output row within pair
  const int wn   = wv >> 1;         // oc 64-half
  const int m31  = lane & 31;
  const int kh8  = lane >> 5;       // k-octet selector

  const int ocb = blockIdx.x;
  const int y0  = blockIdx.y * 2;
  const int n   = blockIdx.z;

  const u16* gA = A + ((size_t)n * PROW + y0) * 2048;

  v16f acc[2][2];
  #pragma unroll
  for (int i = 0; i < 2; i++)
    #pragma unroll
    for (int j = 0; j < 2; j++)
      #pragma unroll
      for (int e = 0; e < 16; e++)
        acc[i][j][e] = 0.0f;

  // B fragment LDS offsets (u16 idx within a tap's 4096 block)
  int ub[2][2];
  #pragma unroll
  for (int nf = 0; nf < 2; nf++)
    #pragma unroll
    for (int kh = 0; kh < 2; kh++) {
      int ocl = wn * 64 + nf * 32 + m31;      // 0..127
      int q = kh * 2 + kh8;
      ub[nf][kh] = (q * 128 + ocl) * 8;
    }

  auto stageA = [&](int cc) {
    const u16* g = gA + (size_t)cc * A_CC_STRIDE + tid * 8;
    u16* d = As + tid * 8;
    #pragma unroll
    for (int k = 0; k < 4; k++)
      gl2lds16(g + k * 2048, d + k * 2048);
  };
  auto stageB = [&](int cc, int ky) {
    #pragma unroll
    for (int kx = 0; kx < 3; kx++) {
      const int kk = ky * 3 + kx;
      const u16* g = Wb + ((kk * 8 + cc) * 8192 + ocb * 4096) + tid * 8;
      u16* d = Bs + kx * 4096 + tid * 8;
      gl2lds16(g, d);
      gl2lds16(g + 2048, d + 2048);
    }
  };

  for (int cc = 0; cc < 8; cc++) {
    __syncthreads();
    stageA(cc);
    stageB(cc, 0);
    __syncthreads();
    #pragma unroll
    for (int ky = 0; ky < 3; ky++) {
      #pragma unroll
      for (int kx = 0; kx < 3; kx++) {
        v8s af[2][2];
        #pragma unroll
        for (int mf = 0; mf < 2; mf++)
          #pragma unroll
          for (int kh = 0; kh < 2; kh++) {
            int col = mf * 32 + m31 + kx;
            col = col > 63 ? 63 : col;          // dead cols (>=56) never stored
            int q = kh * 2 + kh8;
            int ua = ((wm + ky) * 4 + q) * 512 + col * 8;
            af[mf][kh] = *(const v8s*)(As + ua);
          }
        v8s bf[2][2];
        const u16* bsb = Bs + kx * 4096;
        #pragma unroll
        for (int nf = 0; nf < 2; nf++)
          #pragma unroll
          for (int kh = 0; kh < 2; kh++)
            bf[nf][kh] = *(const v8s*)(bsb + ub[nf][kh]);
        #pragma unroll
        for (int mf = 0; mf < 2; mf++)
          #pragma unroll
          for (int nf = 0; nf < 2; nf++) {
            acc[mf][nf] = __builtin_amdgcn_mfma_f32_32x32x16_bf16(af[mf][0], bf[nf][0], acc[mf][nf], 0, 0, 0);
            acc[mf][nf] = __builtin_amdgcn_mfma_f32_32x32x16_bf16(af[mf][1], bf[nf][1], acc[mf][nf], 0, 0, 0);
          }
      }
      if (ky < 2) {
        __syncthreads();
        stageB(cc, ky + 1);
        __syncthreads();
      }
    }
  }

  // epilogue: C/D 32x32: col(lane&31)=oc, row = (reg&3) + 8*(reg>>2) + 4*(lane>>5) = x
  const int yrow = y0 + wm;
  #pragma unroll
  for (int nf = 0; nf < 2; nf++) {
    const int oc = ocb * 128 + wn * 64 + nf * 32 + m31;
    const float bb = bias[oc];
    float* orow = out + ((size_t)(n * 256 + oc) * 56 + yrow) * 56;
    #pragma unroll
    for (int mf = 0; mf < 2; mf++) {
      #pragma unroll
      for (int g = 0; g < 4; g++) {
        const int x0 = mf * 32 + 8 * g + 4 * kh8;
        if (x0 < 56) {
          v4f val = { acc[mf][nf][4*g+0] + bb, acc[mf][nf][4*g+1] + bb,
                      acc[mf][nf][4*g+2] + bb, acc[mf][nf][4*g+3] + bb };
          *(v4f*)(orow + x0) = val;
        }
      }
    }
  }
}

extern "C" void kernel_launch(void* const* d_in, const int* in_sizes, int n_in,
                              void* d_out, int out_size, void* d_ws, size_t ws_size,
                              hipStream_t stream)
{
  const float* x     = (const float*)d_in[0];
  const float* Wf    = (const float*)d_in[1];
  const float* bias  = (const float*)d_in[2];
  const float* rms_w = (const float*)d_in[3];
  float* out = (float*)d_out;

  if (ws_size < A_BYTES + WB_ELEMS * 2) return;

  u16* Abf = (u16*)d_ws;
  u16* Wb  = (u16*)((char*)d_ws + A_BYTES);

  fwht_kernel<<<dim3(56, 32), 256, 0, stream>>>(x, rms_w, Abf);
  wconv_kernel<<<dim3((int)(WB_ELEMS / 256)), 256, 0, stream>>>(Wf, Wb);
  conv_kernel<<<dim3(2, 28, 32), 256, 0, stream>>>(Abf, Wb, bias, out);
}

// Round 5
// 335.176 us; speedup vs baseline: 1.0508x; 1.0508x over previous
//
#include <hip/hip_runtime.h>
#include <hip/hip_bf16.h>

typedef short v8s __attribute__((ext_vector_type(8)));
typedef float v4f __attribute__((ext_vector_type(4)));
typedef float v16f __attribute__((ext_vector_type(16)));
typedef unsigned short u16;

#define PROW 58
#define PCOL 64

// ws layout (octet-major, conflict-free ds_read_b128):
//   A:  [cc 8][n 32][row 58][q 4][col 64][j 8] bf16   (ch = q*8+j within cc)
//   Wb: [kk 9][cc 8][ocb 2][q 4][ocl 128][j 8] bf16   (ic = cc*32+q*8+j, oc = ocb*128+ocl)
static constexpr size_t A_CC_STRIDE = (size_t)32 * PROW * PCOL * 32;   // elems
static constexpr size_t A_BYTES     = 8 * A_CC_STRIDE * 2;
static constexpr size_t WB_ELEMS    = (size_t)9 * 8 * 256 * 32;

__device__ __forceinline__ void gl2lds16(const void* gptr, void* lptr) {
  auto g = (const __attribute__((address_space(1))) unsigned int*)gptr;
  auto l = (__attribute__((address_space(3))) unsigned int*)lptr;
  __builtin_amdgcn_global_load_lds(g, l, 16, 0, 0);
}

__device__ __forceinline__ u16 f2bf(float f) {
  __hip_bfloat16 h = __float2bfloat16(f);
  union { __hip_bfloat16 b; u16 u; } cv; cv.b = h; return cv.u;
}

// s_waitcnt vmcnt(K), no lgkm/exp wait: simm16 = K[3:0] | exp(7)<<4 | lgkm(15)<<8
#define WAITVM(K) __builtin_amdgcn_s_waitcnt(0xF70 | (K))

// ---------------------------------------------------------------------------
// Hg table: B[c,c'] = golay(c) * (-1)^popc(c&c'), entries +-1 exact in bf16,
// stored pre-swizzled in 32x32x16 MFMA B-fragment order:
//   [ks 16][ntile 8][lane 64][j 8],
//   element (lane,j) = B[ ks*16 + (lane>>5)*8 + j ][ nt*32 + (lane&31) ]
// 128 KB .rodata, L2-resident.
// ---------------------------------------------------------------------------
struct alignas(16) HgTab {
  u16 v[16 * 8 * 64 * 8];
  constexpr HgTab() : v{} {
    for (int ks = 0; ks < 16; ks++)
      for (int nt = 0; nt < 8; nt++)
        for (int l = 0; l < 64; l++)
          for (int j = 0; j < 8; j++) {
            int c  = ks * 16 + ((l >> 5) << 3) + j;
            int cp = (nt << 5) + (l & 31);
            int s  = (__builtin_popcount((unsigned)(c & cp)) +
                      __builtin_popcount((unsigned)(c & (c >> 1)))) & 1;
            v[(((ks << 3) + nt) << 9) + (l << 3) + j] = (u16)(s ? 0xBF80 : 0x3F80);
          }
  }
};
static_assert(sizeof(HgTab) == 131072, "HgTab size");
__device__ const HgTab HG{};

// ---------------- kernel 1: golay * FWHT * RMSNorm via MFMA ----------------
// Shared 4-deep staging ring (1 DMA instr per wave per step), counted-vmcnt
// pipeline with 2 DMA-steps always in flight, B-fragments prefetched 1 step
// ahead (so the compiler's bfr wait never drains the DMA queue), exactly one
// s_barrier per step, no vmcnt(0) drains in the loop.
__global__ __launch_bounds__(256, 4) void fwht_kernel(
    const float* __restrict__ x, const float* __restrict__ rms_w,
    u16* __restrict__ A)
{
  __shared__ __align__(16) float xs4[4][16][64];   // shared ring, 16 KB
  __shared__ float ssbuf[2][64];                   // [n-half][pos] partial SS

  const int tid = threadIdx.x;
  const int y = blockIdx.x;
  const int n = blockIdx.y;

  const int lane = tid & 63;
  const int wv   = tid >> 6;
  const int mt   = wv & 1;     // M-tile: positions mt*32..mt*32+31
  const int nh   = wv >> 1;    // N-half: c' in [nh*128, nh*128+128)
  const int l31  = lane & 31;
  const int h    = lane >> 5;  // k-octet selector

  const int pos  = mt * 32 + l31;
  const int posl = pos > 55 ? 55 : pos;          // rows 56..63 are dead (never stored)

  const float* xrow = x + (size_t)n * 802816 + (size_t)y * 56;
  const int rr4 = lane >> 4;
  int c4 = (lane & 15) * 4; if (c4 > 52) c4 = 52; // src clamped; dest stays linear

  // one DMA per wave per step: wave wv stages rows 4wv..4wv+3 of the slice
#define FSTG(KS) gl2lds16(xrow + (size_t)((KS) * 16 + wv * 4 + rr4) * 3136 + c4, \
                          &xs4[(KS) & 3][wv * 4 + rr4][(lane & 15) * 4])

  v8s bfr[2][4];
#define LOADB(KS, BK) { _Pragma("unroll") for (int nt = 0; nt < 4; nt++) \
    bfr[BK][nt] = *(const v8s*)(HG.v + ((size_t)((((KS) * 8) + nh * 4 + nt) * 64 + lane)) * 8); }

  v16f acc[4];
  #pragma unroll
  for (int nt = 0; nt < 4; nt++)
    #pragma unroll
    for (int e = 0; e < 16; e++)
      acc[nt][e] = 0.0f;

  // prologue: DMA0, bfr0, DMA1, DMA2  (bfr0 older than DMA1/2 -> K(0)=6)
  FSTG(0);
  LOADB(0, 0)
  FSTG(1);
  FSTG(2);

#define FCOMP(S) { const float* cb = &xs4[(S) & 3][0][0]; v8s ah, al; \
    _Pragma("unroll") for (int j = 0; j < 8; j++) { \
      float v = cb[(h * 8 + j) * 64 + posl]; \
      unsigned u = __float_as_uint(v); \
      unsigned hu = u & 0xFFFF0000u; \
      float r = v - __uint_as_float(hu); \
      ah[j] = (short)(hu >> 16); \
      al[j] = (short)f2bf(r); } \
    _Pragma("unroll") for (int nt = 0; nt < 4; nt++) { \
      acc[nt] = __builtin_amdgcn_mfma_f32_32x32x16_bf16(ah, bfr[(S) & 1][nt], acc[nt], 0, 0, 0); \
      acc[nt] = __builtin_amdgcn_mfma_f32_32x32x16_bf16(al, bfr[(S) & 1][nt], acc[nt], 0, 0, 0); } }

#define FSTEP(S, KV) { \
    if ((S) < 15) LOADB((S) + 1, ((S) + 1) & 1) \
    __builtin_amdgcn_sched_barrier(0); \
    WAITVM(KV); \
    __builtin_amdgcn_sched_barrier(0); \
    __builtin_amdgcn_s_barrier(); \
    if ((S) + 3 <= 15) { FSTG((S) + 3); } \
    __builtin_amdgcn_sched_barrier(0); \
    FCOMP(S) }

  FSTEP(0, 6)  FSTEP(1, 5)  FSTEP(2, 5)  FSTEP(3, 5)
  FSTEP(4, 5)  FSTEP(5, 5)  FSTEP(6, 5)  FSTEP(7, 5)
  FSTEP(8, 5)  FSTEP(9, 5)  FSTEP(10, 5) FSTEP(11, 5)
  FSTEP(12, 5) FSTEP(13, 5) FSTEP(14, 4) FSTEP(15, 0)

  // row sum-of-squares: C/D layout col=lane&31 (=c'), row=(g&3)+8*(g>>2)+4*h
  #pragma unroll
  for (int g = 0; g < 16; g++) {
    float s = acc[0][g] * acc[0][g] + acc[1][g] * acc[1][g]
            + acc[2][g] * acc[2][g] + acc[3][g] * acc[3][g];
    #pragma unroll
    for (int m = 1; m <= 16; m <<= 1) s += __shfl_xor(s, m, 64);  // within 32-half
    if (l31 == 0)
      ssbuf[nh][mt * 32 + (g & 3) + 8 * (g >> 2) + 4 * h] = s;
  }
  __syncthreads();

  float rwv[4];
  #pragma unroll
  for (int nt = 0; nt < 4; nt++)
    rwv[nt] = rms_w[nh * 128 + nt * 32 + l31];

  const int jj  = lane & 7;   // j within octet
  const int icq = l31 >> 3;   // ch octet q

  #pragma unroll
  for (int g = 0; g < 16; g++) {
    const int rg   = (g & 3) + 8 * (g >> 2) + 4 * h;
    const int posg = mt * 32 + rg;
    float ssum = ssbuf[0][posg] + ssbuf[1][posg];
    float sc = rsqrtf(ssum * (1.0f / 256.0f) + 1e-5f);
    if (posg < 56) {
      const int col = posg + 1;
      const size_t rowoff = ((size_t)icq * 64 + col) * 8 + jj;   // octet-major
      #pragma unroll
      for (int nt = 0; nt < 4; nt++) {
        const int cc = nh * 4 + nt;                 // c' = cc*32 + l31
        size_t go = (((size_t)cc * 32 + n) * PROW + (y + 1)) * 2048 + rowoff;
        A[go] = f2bf(acc[nt][g] * sc * rwv[nt]);
      }
    }
  }

  // halo cols 0 and 57..63 of this row (all 4 q-octets)
  {
    const v8s z = {0,0,0,0,0,0,0,0};
    int cc = tid >> 5;
    int s  = tid & 31;
    int q  = s >> 3, cidx = s & 7;
    int col = (cidx == 0) ? 0 : (56 + cidx);       // {0,57,...,63}
    size_t rb = (((size_t)cc * 32 + n) * PROW + (y + 1)) * 2048;
    *(v8s*)(A + rb + ((size_t)q * 64 + col) * 8) = z;
  }
  // halo rows 0 / 57 (full rows, layout-agnostic)
  if (y == 0 || y == 55) {
    const v8s z = {0,0,0,0,0,0,0,0};
    const int r = (y == 0) ? 0 : 57;
    #pragma unroll
    for (int i = 0; i < 8; i++) {
      int c = tid + 256 * i;             // 2048 chunks
      int cc = c >> 8, rem = c & 255;
      size_t go = (((size_t)cc * 32 + n) * PROW + r) * 2048 + rem * 8;
      *(v8s*)(A + go) = z;
    }
  }
#undef FSTG
#undef LOADB
#undef FCOMP
#undef FSTEP
}

// ---------------- kernel 2: W fp32 -> swizzled bf16 (octet-major) ----------------
__global__ __launch_bounds__(256) void wconv_kernel(
    const float* __restrict__ Wf, u16* __restrict__ Wb)
{
  int t = blockIdx.x * 256 + threadIdx.x;
  int kk = t >> 16;
  int cc = (t >> 13) & 7;
  int r  = t & 8191;
  int ocb = r >> 12;
  int q   = (r >> 10) & 3;
  int ocl = (r >> 3) & 127;
  int j   = r & 7;
  int oc = ocb * 128 + ocl;
  int ic = cc * 32 + q * 8 + j;
  int ky = kk / 3, kx = kk - ky * 3;
  float w = Wf[((oc * 256 + ic) * 3 + ky) * 3 + kx];
  Wb[t] = f2bf(w);
}

// ---------------- kernel 3: implicit-GEMM conv, deep-pipelined ----------------
// 24 phases (cc x ky), As/Bs both double-buffered (80 KB LDS, 2 blocks/CU).
// Per phase: issue next stage -> counted vmcnt (6 or 10, never 0 mid-loop)
// -> barrier -> 24 ds_read + 24 MFMA (setprio) -> barrier. No full drains.
__global__ __launch_bounds__(256, 2) void conv_kernel(
    const u16* __restrict__ A, const u16* __restrict__ Wb,
    const float* __restrict__ bias, float* __restrict__ out)
{
  __shared__ __align__(16) u16 As2[2][8192];          // 2 x 16 KB: 4 rows [q4][col64][j8]
  __shared__ __align__(16) u16 Bs2[2][12288];         // 2 x 24 KB: 3 taps [q4][ocl128][j8]

  const int tid  = threadIdx.x;
  const int lane = tid & 63;
  const int wv   = tid >> 6;
  const int wm   = wv & 1;          // output row within pair
  const int wn   = wv >> 1;         // oc 64-half
  const int m31  = lane & 31;
  const int kh8  = lane >> 5;       // k-octet selector

  const int ocb = blockIdx.x;
  const int y0  = blockIdx.y * 2;
  const int n   = blockIdx.z;

  const u16* gA = A + ((size_t)n * PROW + y0) * 2048;

  v16f acc[2][2];
  #pragma unroll
  for (int i = 0; i < 2; i++)
    #pragma unroll
    for (int j = 0; j < 2; j++)
      #pragma unroll
      for (int e = 0; e < 16; e++)
        acc[i][j][e] = 0.0f;

  // B fragment LDS offsets (u16 idx within a tap's 4096 block)
  int ub[2][2];
  #pragma unroll
  for (int nf = 0; nf < 2; nf++)
    #pragma unroll
    for (int kh = 0; kh < 2; kh++) {
      int ocl = wn * 64 + nf * 32 + m31;      // 0..127
      int q = kh * 2 + kh8;
      ub[nf][kh] = (q * 128 + ocl) * 8;
    }

#define STAGE_A(CCV) { const u16* g = gA + (size_t)(CCV) * A_CC_STRIDE + tid * 8; \
    u16* d = &As2[(CCV) & 1][0] + tid * 8; \
    _Pragma("unroll") for (int k = 0; k < 4; k++) gl2lds16(g + k * 2048, d + k * 2048); }

#define STAGE_B(CCV, KYV, BUF) { _Pragma("unroll") for (int kx = 0; kx < 3; kx++) { \
    const u16* g = Wb + ((((KYV) * 3 + kx) * 8 + (CCV)) * 8192 + ocb * 4096) + tid * 8; \
    u16* d = &Bs2[BUF][kx * 4096] + tid * 8; \
    gl2lds16(g, d); gl2lds16(g + 2048, d + 2048); } }

#define CONV_PHASE(P) { \
    if ((P) < 23) { \
      STAGE_B(((P) + 1) / 3, ((P) + 1) % 3, ((P) + 1) & 1) \
      if (((P) + 1) % 3 == 0) STAGE_A((((P) + 1) / 3) & 1 ? (((P) + 1) / 3) : (((P) + 1) / 3)) \
    } \
    __builtin_amdgcn_sched_barrier(0); \
    WAITVM((P) == 23 ? 0 : (((P) + 1) % 3 == 0 ? 10 : 6)); \
    __builtin_amdgcn_sched_barrier(0); \
    __builtin_amdgcn_s_barrier(); \
    { const u16* asb = &As2[((P) / 3) & 1][0]; \
      const u16* bsb0 = &Bs2[(P) & 1][0]; \
      _Pragma("unroll") for (int kx = 0; kx < 3; kx++) { \
        v8s af[2][2]; \
        _Pragma("unroll") for (int mf = 0; mf < 2; mf++) \
          _Pragma("unroll") for (int kh = 0; kh < 2; kh++) { \
            int col = mf * 32 + m31 + kx; \
            col = col > 63 ? 63 : col; \
            int q = kh * 2 + kh8; \
            int ua = ((wm + ((P) % 3)) * 4 + q) * 512 + col * 8; \
            af[mf][kh] = *(const v8s*)(asb + ua); } \
        v8s bf[2][2]; const u16* bsb = bsb0 + kx * 4096; \
        _Pragma("unroll") for (int nf = 0; nf < 2; nf++) \
          _Pragma("unroll") for (int kh = 0; kh < 2; kh++) \
            bf[nf][kh] = *(const v8s*)(bsb + ub[nf][kh]); \
        __builtin_amdgcn_s_setprio(1); \
        _Pragma("unroll") for (int mf = 0; mf < 2; mf++) \
          _Pragma("unroll") for (int nf = 0; nf < 2; nf++) { \
            acc[mf][nf] = __builtin_amdgcn_mfma_f32_32x32x16_bf16(af[mf][0], bf[nf][0], acc[mf][nf], 0, 0, 0); \
            acc[mf][nf] = __builtin_amdgcn_mfma_f32_32x32x16_bf16(af[mf][1], bf[nf][1], acc[mf][nf], 0, 0, 0); } \
        __builtin_amdgcn_s_setprio(0); \
      } \
    } \
    __builtin_amdgcn_s_barrier(); }

  // prologue: stage phase 0 (B taps of (cc0,ky0) + A rows of cc0)
  STAGE_B(0, 0, 0)
  STAGE_A(0)

  CONV_PHASE(0)  CONV_PHASE(1)  CONV_PHASE(2)  CONV_PHASE(3)
  CONV_PHASE(4)  CONV_PHASE(5)  CONV_PHASE(6)  CONV_PHASE(7)
  CONV_PHASE(8)  CONV_PHASE(9)  CONV_PHASE(10) CONV_PHASE(11)
  CONV_PHASE(12) CONV_PHASE(13) CONV_PHASE(14) CONV_PHASE(15)
  CONV_PHASE(16) CONV_PHASE(17) CONV_PHASE(18) CONV_PHASE(19)
  CONV_PHASE(20) CONV_PHASE(21) CONV_PHASE(22) CONV_PHASE(23)

#undef STAGE_A
#undef STAGE_B
#undef CONV_PHASE

  // epilogue: C/D 32x32: col(lane&31)=oc, row = (reg&3) + 8*(reg>>2) + 4*(lane>>5) = x
  const int yrow = y0 + wm;
  #pragma unroll
  for (int nf = 0; nf < 2; nf++) {
    const int oc = ocb * 128 + wn * 64 + nf * 32 + m31;
    const float bb = bias[oc];
    float* orow = out + ((size_t)(n * 256 + oc) * 56 + yrow) * 56;
    #pragma unroll
    for (int mf = 0; mf < 2; mf++) {
      #pragma unroll
      for (int g = 0; g < 4; g++) {
        const int x0 = mf * 32 + 8 * g + 4 * kh8;
        if (x0 < 56) {
          v4f val = { acc[mf][nf][4*g+0] + bb, acc[mf][nf][4*g+1] + bb,
                      acc[mf][nf][4*g+2] + bb, acc[mf][nf][4*g+3] + bb };
          *(v4f*)(orow + x0) = val;
        }
      }
    }
  }
}

extern "C" void kernel_launch(void* const* d_in, const int* in_sizes, int n_in,
                              void* d_out, int out_size, void* d_ws, size_t ws_size,
                              hipStream_t stream)
{
  const float* x     = (const float*)d_in[0];
  const float* Wf    = (const float*)d_in[1];
  const float* bias  = (const float*)d_in[2];
  const float* rms_w = (const float*)d_in[3];
  float* out = (float*)d_out;

  if (ws_size < A_BYTES + WB_ELEMS * 2) return;

  u16* Abf = (u16*)d_ws;
  u16* Wb  = (u16*)((char*)d_ws + A_BYTES);

  fwht_kernel<<<dim3(56, 32), 256, 0, stream>>>(x, rms_w, Abf);
  wconv_kernel<<<dim3((int)(WB_ELEMS / 256)), 256, 0, stream>>>(Wf, Wb);
  conv_kernel<<<dim3(2, 28, 32), 256, 0, stream>>>(Abf, Wb, bias, out);
}

// Round 6
// 333.120 us; speedup vs baseline: 1.0573x; 1.0062x over previous
//
#include <hip/hip_runtime.h>
#include <hip/hip_bf16.h>

typedef short v8s __attribute__((ext_vector_type(8)));
typedef float v4f __attribute__((ext_vector_type(4)));
typedef float v16f __attribute__((ext_vector_type(16)));
typedef unsigned short u16;

#define PROW 58
#define PCOL 64

// ws layout (octet-major, conflict-free ds_read_b128):
//   A:  [cc 8][n 32][row 58][q 4][col 64][j 8] bf16   (ch = q*8+j within cc)
//   Wb: [kk 9][cc 8][ocb 2][q 4][ocl 128][j 8] bf16   (ic = cc*32+q*8+j, oc = ocb*128+ocl)
static constexpr size_t A_CC_STRIDE = (size_t)32 * PROW * PCOL * 32;   // elems
static constexpr size_t A_BYTES     = 8 * A_CC_STRIDE * 2;
static constexpr size_t WB_ELEMS    = (size_t)9 * 8 * 256 * 32;

__device__ __forceinline__ void gl2lds16(const void* gptr, void* lptr) {
  auto g = (const __attribute__((address_space(1))) unsigned int*)gptr;
  auto l = (__attribute__((address_space(3))) unsigned int*)lptr;
  __builtin_amdgcn_global_load_lds(g, l, 16, 0, 0);
}

__device__ __forceinline__ u16 f2bf(float f) {
  __hip_bfloat16 h = __float2bfloat16(f);
  union { __hip_bfloat16 b; u16 u; } cv; cv.b = h; return cv.u;
}

// exact text-asm wait: only vmcnt, no lgkm/exp side effects
#define WAITVM(K) asm volatile("s_waitcnt vmcnt(" #K ")" ::: "memory")

// ---------------------------------------------------------------------------
// Hg table: B[c,c'] = golay(c) * (-1)^popc(c&c'), entries +-1 exact in bf16,
// stored pre-swizzled in 32x32x16 MFMA B-fragment order:
//   [ks 16][ntile 8][lane 64][j 8],
//   element (lane,j) = B[ ks*16 + (lane>>5)*8 + j ][ nt*32 + (lane&31) ]
// 128 KB .rodata, L2-resident.
// ---------------------------------------------------------------------------
struct alignas(16) HgTab {
  u16 v[16 * 8 * 64 * 8];
  constexpr HgTab() : v{} {
    for (int ks = 0; ks < 16; ks++)
      for (int nt = 0; nt < 8; nt++)
        for (int l = 0; l < 64; l++)
          for (int j = 0; j < 8; j++) {
            int c  = ks * 16 + ((l >> 5) << 3) + j;
            int cp = (nt << 5) + (l & 31);
            int s  = (__builtin_popcount((unsigned)(c & cp)) +
                      __builtin_popcount((unsigned)(c & (c >> 1)))) & 1;
            v[(((ks << 3) + nt) << 9) + (l << 3) + j] = (u16)(s ? 0xBF80 : 0x3F80);
          }
  }
};
static_assert(sizeof(HgTab) == 131072, "HgTab size");
__device__ const HgTab HG{};

// ---------------- kernel 1: golay * FWHT * RMSNorm via MFMA ----------------
// Shared 4-deep staging ring (1 DMA instr per wave per step), counted-vmcnt
// pipeline with 2 DMA-steps in flight, B-fragments prefetched 1 step ahead,
// exactly one s_barrier per step, no vmcnt(0) drains in the loop.
__global__ __launch_bounds__(256, 4) void fwht_kernel(
    const float* __restrict__ x, const float* __restrict__ rms_w,
    u16* __restrict__ A)
{
  __shared__ __align__(16) float xs4[4][16][64];   // shared ring, 16 KB
  __shared__ float ssbuf[2][64];                   // [n-half][pos] partial SS

  const int tid = threadIdx.x;
  const int y = blockIdx.x;
  const int n = blockIdx.y;

  const int lane = tid & 63;
  const int wv   = tid >> 6;
  const int mt   = wv & 1;     // M-tile: positions mt*32..mt*32+31
  const int nh   = wv >> 1;    // N-half: c' in [nh*128, nh*128+128)
  const int l31  = lane & 31;
  const int h    = lane >> 5;  // k-octet selector

  const int pos  = mt * 32 + l31;
  const int posl = pos > 55 ? 55 : pos;          // rows 56..63 are dead (never stored)

  const float* xrow = x + (size_t)n * 802816 + (size_t)y * 56;
  const int rr4 = lane >> 4;
  int c4 = (lane & 15) * 4; if (c4 > 52) c4 = 52; // src clamped; dest stays linear

  // one DMA per wave per step: wave wv stages rows 4wv..4wv+3 of the slice
#define FSTG(KS) gl2lds16(xrow + (size_t)((KS) * 16 + wv * 4 + rr4) * 3136 + c4, \
                          &xs4[(KS) & 3][wv * 4 + rr4][(lane & 15) * 4])

  v8s bfr[2][4];
#define LOADB(KS, BK) { _Pragma("unroll") for (int nt = 0; nt < 4; nt++) \
    bfr[BK][nt] = *(const v8s*)(HG.v + ((size_t)((((KS) * 8) + nh * 4 + nt) * 64 + lane)) * 8); }

  v16f acc[4];
  #pragma unroll
  for (int nt = 0; nt < 4; nt++)
    #pragma unroll
    for (int e = 0; e < 16; e++)
      acc[nt][e] = 0.0f;

  // prologue: DMA0, bfr0, DMA1, DMA2  (bfr0 older than DMA1/2 -> K(0)=6)
  FSTG(0);
  LOADB(0, 0)
  FSTG(1);
  FSTG(2);

#define FCOMP(S) { const float* cb = &xs4[(S) & 3][0][0]; v8s ah, al; \
    _Pragma("unroll") for (int j = 0; j < 8; j++) { \
      float v = cb[(h * 8 + j) * 64 + posl]; \
      unsigned u = __float_as_uint(v); \
      unsigned hu = u & 0xFFFF0000u; \
      float r = v - __uint_as_float(hu); \
      ah[j] = (short)(hu >> 16); \
      al[j] = (short)f2bf(r); } \
    _Pragma("unroll") for (int nt = 0; nt < 4; nt++) { \
      acc[nt] = __builtin_amdgcn_mfma_f32_32x32x16_bf16(ah, bfr[(S) & 1][nt], acc[nt], 0, 0, 0); \
      acc[nt] = __builtin_amdgcn_mfma_f32_32x32x16_bf16(al, bfr[(S) & 1][nt], acc[nt], 0, 0, 0); } }

#define FSTEP(S, KV) { \
    if ((S) < 15) LOADB((S) + 1, ((S) + 1) & 1) \
    __builtin_amdgcn_sched_barrier(0); \
    WAITVM(KV); \
    __builtin_amdgcn_sched_barrier(0); \
    __builtin_amdgcn_s_barrier(); \
    if ((S) + 3 <= 15) { FSTG((S) + 3); } \
    __builtin_amdgcn_sched_barrier(0); \
    FCOMP(S) }

  FSTEP(0, 6)  FSTEP(1, 5)  FSTEP(2, 5)  FSTEP(3, 5)
  FSTEP(4, 5)  FSTEP(5, 5)  FSTEP(6, 5)  FSTEP(7, 5)
  FSTEP(8, 5)  FSTEP(9, 5)  FSTEP(10, 5) FSTEP(11, 5)
  FSTEP(12, 5) FSTEP(13, 5) FSTEP(14, 4) FSTEP(15, 0)

  // row sum-of-squares: C/D layout col=lane&31 (=c'), row=(g&3)+8*(g>>2)+4*h
  #pragma unroll
  for (int g = 0; g < 16; g++) {
    float s = acc[0][g] * acc[0][g] + acc[1][g] * acc[1][g]
            + acc[2][g] * acc[2][g] + acc[3][g] * acc[3][g];
    #pragma unroll
    for (int m = 1; m <= 16; m <<= 1) s += __shfl_xor(s, m, 64);  // within 32-half
    if (l31 == 0)
      ssbuf[nh][mt * 32 + (g & 3) + 8 * (g >> 2) + 4 * h] = s;
  }
  __syncthreads();

  float rwv[4];
  #pragma unroll
  for (int nt = 0; nt < 4; nt++)
    rwv[nt] = rms_w[nh * 128 + nt * 32 + l31];

  const int jj  = lane & 7;   // j within octet
  const int icq = l31 >> 3;   // ch octet q

  #pragma unroll
  for (int g = 0; g < 16; g++) {
    const int rg   = (g & 3) + 8 * (g >> 2) + 4 * h;
    const int posg = mt * 32 + rg;
    float ssum = ssbuf[0][posg] + ssbuf[1][posg];
    float sc = rsqrtf(ssum * (1.0f / 256.0f) + 1e-5f);
    if (posg < 56) {
      const int col = posg + 1;
      const size_t rowoff = ((size_t)icq * 64 + col) * 8 + jj;   // octet-major
      #pragma unroll
      for (int nt = 0; nt < 4; nt++) {
        const int cc = nh * 4 + nt;                 // c' = cc*32 + l31
        size_t go = (((size_t)cc * 32 + n) * PROW + (y + 1)) * 2048 + rowoff;
        A[go] = f2bf(acc[nt][g] * sc * rwv[nt]);
      }
    }
  }

  // halo cols 0 and 57..63 of this row (all 4 q-octets)
  {
    const v8s z = {0,0,0,0,0,0,0,0};
    int cc = tid >> 5;
    int s  = tid & 31;
    int q  = s >> 3, cidx = s & 7;
    int col = (cidx == 0) ? 0 : (56 + cidx);       // {0,57,...,63}
    size_t rb = (((size_t)cc * 32 + n) * PROW + (y + 1)) * 2048;
    *(v8s*)(A + rb + ((size_t)q * 64 + col) * 8) = z;
  }
  // halo rows 0 / 57 (full rows, layout-agnostic)
  if (y == 0 || y == 55) {
    const v8s z = {0,0,0,0,0,0,0,0};
    const int r = (y == 0) ? 0 : 57;
    #pragma unroll
    for (int i = 0; i < 8; i++) {
      int c = tid + 256 * i;             // 2048 chunks
      int cc = c >> 8, rem = c & 255;
      size_t go = (((size_t)cc * 32 + n) * PROW + r) * 2048 + rem * 8;
      *(v8s*)(A + go) = z;
    }
  }
#undef FSTG
#undef LOADB
#undef FCOMP
#undef FSTEP
}

// ---------------- kernel 2: W fp32 -> swizzled bf16 (octet-major) ----------------
__global__ __launch_bounds__(256) void wconv_kernel(
    const float* __restrict__ Wf, u16* __restrict__ Wb)
{
  int t = blockIdx.x * 256 + threadIdx.x;
  int kk = t >> 16;
  int cc = (t >> 13) & 7;
  int r  = t & 8191;
  int ocb = r >> 12;
  int q   = (r >> 10) & 3;
  int ocl = (r >> 3) & 127;
  int j   = r & 7;
  int oc = ocb * 128 + ocl;
  int ic = cc * 32 + q * 8 + j;
  int ky = kk / 3, kx = kk - ky * 3;
  float w = Wf[((oc * 256 + ic) * 3 + ky) * 3 + kx];
  Wb[t] = f2bf(w);
}

// ---------------- kernel 3: implicit-GEMM conv ----------------
// A double-buffered in LDS (32 KB -> 4 blocks/CU); B streamed from L2 straight
// to registers (Wb is 1.18 MB, L2-resident; fragment loads = two 512-B
// segments per instr, fully coalesced). ONE barrier per cc (8 total), whose
// preceding vmcnt(0) lands ~9 phases after the DMAs it drains -> stall-free.
__global__ __launch_bounds__(256, 4) void conv_kernel(
    const u16* __restrict__ A, const u16* __restrict__ Wb,
    const float* __restrict__ bias, float* __restrict__ out)
{
  __shared__ __align__(16) u16 As2[2][8192];          // 2 x 16 KB: 4 rows [q4][col64][j8]

  const int tid  = threadIdx.x;
  const int lane = tid & 63;
  const int wv   = tid >> 6;
  const int wm   = wv & 1;          // output row within pair
  const int wn   = wv >> 1;         // oc 64-half
  const int m31  = lane & 31;
  const int kh8  = lane >> 5;       // k-octet selector

  const int ocb = blockIdx.x;
  const int y0  = blockIdx.y * 2;
  const int n   = blockIdx.z;

  const u16* gA = A + ((size_t)n * PROW + y0) * 2048;

  v16f acc[2][2];
  #pragma unroll
  for (int i = 0; i < 2; i++)
    #pragma unroll
    for (int j = 0; j < 2; j++)
      #pragma unroll
      for (int e = 0; e < 16; e++)
        acc[i][j][e] = 0.0f;

  // B fragment offsets (u16 idx within a (kk,cc,ocb) 4096-elem block)
  int ub[2][2];
  #pragma unroll
  for (int nf = 0; nf < 2; nf++)
    #pragma unroll
    for (int kh = 0; kh < 2; kh++) {
      int ocl = wn * 64 + nf * 32 + m31;      // 0..127
      int q = kh * 2 + kh8;
      ub[nf][kh] = (q * 128 + ocl) * 8;
    }

#define STAGE_A(CCV) { const u16* g = gA + (size_t)(CCV) * A_CC_STRIDE + tid * 8; \
    u16* d = &As2[(CCV) & 1][0] + tid * 8; \
    _Pragma("unroll") for (int k = 0; k < 4; k++) gl2lds16(g + k * 2048, d + k * 2048); }

#define CONV_CC(CC) { \
    WAITVM(0); \
    __builtin_amdgcn_s_barrier(); \
    if ((CC) < 7) STAGE_A((CC) + 1) \
    __builtin_amdgcn_sched_barrier(0); \
    { const u16* asb = &As2[(CC) & 1][0]; \
      _Pragma("unroll") for (int ky = 0; ky < 3; ky++) \
        _Pragma("unroll") for (int kx = 0; kx < 3; kx++) { \
          const u16* bt = Wb + (size_t)((((ky * 3 + kx) * 8 + (CC)) * 8192) + ocb * 4096); \
          v8s bf[2][2]; \
          _Pragma("unroll") for (int nf = 0; nf < 2; nf++) \
            _Pragma("unroll") for (int kh = 0; kh < 2; kh++) \
              bf[nf][kh] = *(const v8s*)(bt + ub[nf][kh]); \
          v8s af[2][2]; \
          _Pragma("unroll") for (int mf = 0; mf < 2; mf++) \
            _Pragma("unroll") for (int kh = 0; kh < 2; kh++) { \
              int col = mf * 32 + m31 + kx; \
              col = col > 63 ? 63 : col; \
              int q = kh * 2 + kh8; \
              af[mf][kh] = *(const v8s*)(asb + ((wm + ky) * 4 + q) * 512 + col * 8); } \
          _Pragma("unroll") for (int mf = 0; mf < 2; mf++) \
            _Pragma("unroll") for (int nf = 0; nf < 2; nf++) { \
              acc[mf][nf] = __builtin_amdgcn_mfma_f32_32x32x16_bf16(af[mf][0], bf[nf][0], acc[mf][nf], 0, 0, 0); \
              acc[mf][nf] = __builtin_amdgcn_mfma_f32_32x32x16_bf16(af[mf][1], bf[nf][1], acc[mf][nf], 0, 0, 0); } \
        } } }

  // prologue: stage cc=0
  STAGE_A(0)

  CONV_CC(0) CONV_CC(1) CONV_CC(2) CONV_CC(3)
  CONV_CC(4) CONV_CC(5) CONV_CC(6) CONV_CC(7)

#undef STAGE_A
#undef CONV_CC

  // epilogue: C/D 32x32: col(lane&31)=oc, row = (reg&3) + 8*(reg>>2) + 4*(lane>>5) = x
  const int yrow = y0 + wm;
  #pragma unroll
  for (int nf = 0; nf < 2; nf++) {
    const int oc = ocb * 128 + wn * 64 + nf * 32 + m31;
    const float bb = bias[oc];
    float* orow = out + ((size_t)(n * 256 + oc) * 56 + yrow) * 56;
    #pragma unroll
    for (int mf = 0; mf < 2; mf++) {
      #pragma unroll
      for (int g = 0; g < 4; g++) {
        const int x0 = mf * 32 + 8 * g + 4 * kh8;
        if (x0 < 56) {
          v4f val = { acc[mf][nf][4*g+0] + bb, acc[mf][nf][4*g+1] + bb,
                      acc[mf][nf][4*g+2] + bb, acc[mf][nf][4*g+3] + bb };
          *(v4f*)(orow + x0) = val;
        }
      }
    }
  }
}

extern "C" void kernel_launch(void* const* d_in, const int* in_sizes, int n_in,
                              void* d_out, int out_size, void* d_ws, size_t ws_size,
                              hipStream_t stream)
{
  const float* x     = (const float*)d_in[0];
  const float* Wf    = (const float*)d_in[1];
  const float* bias  = (const float*)d_in[2];
  const float* rms_w = (const float*)d_in[3];
  float* out = (float*)d_out;

  if (ws_size < A_BYTES + WB_ELEMS * 2) return;

  u16* Abf = (u16*)d_ws;
  u16* Wb  = (u16*)((char*)d_ws + A_BYTES);

  fwht_kernel<<<dim3(56, 32), 256, 0, stream>>>(x, rms_w, Abf);
  wconv_kernel<<<dim3((int)(WB_ELEMS / 256)), 256, 0, stream>>>(Wf, Wb);
  conv_kernel<<<dim3(2, 28, 32), 256, 0, stream>>>(Abf, Wb, bias, out);
}

// Round 7
// 331.837 us; speedup vs baseline: 1.0613x; 1.0039x over previous
//
#include <hip/hip_runtime.h>
#include <hip/hip_bf16.h>

typedef short v8s __attribute__((ext_vector_type(8)));
typedef float v4f __attribute__((ext_vector_type(4)));
typedef float v16f __attribute__((ext_vector_type(16)));
typedef unsigned short u16;

#define PROW 58
#define PCOL 64

// ws layout (octet-major, conflict-free ds_read_b128):
//   A:  [cc 8][n 32][row 58][q 4][col 64][j 8] bf16   (ch = q*8+j within cc)
//   Wb: [kk 9][cc 8][ocb 2][q 4][ocl 128][j 8] bf16   (ic = cc*32+q*8+j, oc = ocb*128+ocl)
static constexpr size_t A_CC_STRIDE = (size_t)32 * PROW * PCOL * 32;   // elems
static constexpr size_t A_BYTES     = 8 * A_CC_STRIDE * 2;
static constexpr size_t WB_ELEMS    = (size_t)9 * 8 * 256 * 32;

__device__ __forceinline__ void gl2lds16(const void* gptr, void* lptr) {
  auto g = (const __attribute__((address_space(1))) unsigned int*)gptr;
  auto l = (__attribute__((address_space(3))) unsigned int*)lptr;
  __builtin_amdgcn_global_load_lds(g, l, 16, 0, 0);
}

__device__ __forceinline__ u16 f2bf(float f) {
  __hip_bfloat16 h = __float2bfloat16(f);
  union { __hip_bfloat16 b; u16 u; } cv; cv.b = h; return cv.u;
}

// exact text-asm wait: only vmcnt, no lgkm/exp side effects
#define WAITVM(K) asm volatile("s_waitcnt vmcnt(" #K ")" ::: "memory")

// ---------------------------------------------------------------------------
// Hg table: B[c,c'] = golay(c) * (-1)^popc(c&c'), entries +-1 exact in bf16,
// stored pre-swizzled in 32x32x16 MFMA B-fragment order:
//   [ks 16][ntile 8][lane 64][j 8],
//   element (lane,j) = B[ ks*16 + (lane>>5)*8 + j ][ nt*32 + (lane&31) ]
// 128 KB .rodata, L2-resident.
// ---------------------------------------------------------------------------
struct alignas(16) HgTab {
  u16 v[16 * 8 * 64 * 8];
  constexpr HgTab() : v{} {
    for (int ks = 0; ks < 16; ks++)
      for (int nt = 0; nt < 8; nt++)
        for (int l = 0; l < 64; l++)
          for (int j = 0; j < 8; j++) {
            int c  = ks * 16 + ((l >> 5) << 3) + j;
            int cp = (nt << 5) + (l & 31);
            int s  = (__builtin_popcount((unsigned)(c & cp)) +
                      __builtin_popcount((unsigned)(c & (c >> 1)))) & 1;
            v[(((ks << 3) + nt) << 9) + (l << 3) + j] = (u16)(s ? 0xBF80 : 0x3F80);
          }
  }
};
static_assert(sizeof(HgTab) == 131072, "HgTab size");
__device__ const HgTab HG{};

// ---------------- kernel 1: golay * FWHT * RMSNorm via MFMA ----------------
// Shared 4-deep staging ring (1 DMA instr per wave per step), counted-vmcnt
// pipeline with 2 DMA-steps in flight, B-fragments prefetched 1 step ahead,
// exactly one s_barrier per step, no vmcnt(0) drains in the loop.
__global__ __launch_bounds__(256, 4) void fwht_kernel(
    const float* __restrict__ x, const float* __restrict__ rms_w,
    u16* __restrict__ A)
{
  __shared__ __align__(16) float xs4[4][16][64];   // shared ring, 16 KB
  __shared__ float ssbuf[2][64];                   // [n-half][pos] partial SS

  const int tid = threadIdx.x;
  const int y = blockIdx.x;
  const int n = blockIdx.y;

  const int lane = tid & 63;
  const int wv   = tid >> 6;
  const int mt   = wv & 1;     // M-tile: positions mt*32..mt*32+31
  const int nh   = wv >> 1;    // N-half: c' in [nh*128, nh*128+128)
  const int l31  = lane & 31;
  const int h    = lane >> 5;  // k-octet selector

  const int pos  = mt * 32 + l31;
  const int posl = pos > 55 ? 55 : pos;          // rows 56..63 are dead (never stored)

  const float* xrow = x + (size_t)n * 802816 + (size_t)y * 56;
  const int rr4 = lane >> 4;
  int c4 = (lane & 15) * 4; if (c4 > 52) c4 = 52; // src clamped; dest stays linear

  // one DMA per wave per step: wave wv stages rows 4wv..4wv+3 of the slice
#define FSTG(KS) gl2lds16(xrow + (size_t)((KS) * 16 + wv * 4 + rr4) * 3136 + c4, \
                          &xs4[(KS) & 3][wv * 4 + rr4][(lane & 15) * 4])

  v8s bfr[2][4];
#define LOADB(KS, BK) { _Pragma("unroll") for (int nt = 0; nt < 4; nt++) \
    bfr[BK][nt] = *(const v8s*)(HG.v + ((size_t)((((KS) * 8) + nh * 4 + nt) * 64 + lane)) * 8); }

  v16f acc[4];
  #pragma unroll
  for (int nt = 0; nt < 4; nt++)
    #pragma unroll
    for (int e = 0; e < 16; e++)
      acc[nt][e] = 0.0f;

  // prologue: DMA0, bfr0, DMA1, DMA2  (bfr0 older than DMA1/2 -> K(0)=6)
  FSTG(0);
  LOADB(0, 0)
  FSTG(1);
  FSTG(2);

#define FCOMP(S) { const float* cb = &xs4[(S) & 3][0][0]; v8s ah, al; \
    _Pragma("unroll") for (int j = 0; j < 8; j++) { \
      float v = cb[(h * 8 + j) * 64 + posl]; \
      unsigned u = __float_as_uint(v); \
      unsigned hu = u & 0xFFFF0000u; \
      float r = v - __uint_as_float(hu); \
      ah[j] = (short)(hu >> 16); \
      al[j] = (short)f2bf(r); } \
    _Pragma("unroll") for (int nt = 0; nt < 4; nt++) { \
      acc[nt] = __builtin_amdgcn_mfma_f32_32x32x16_bf16(ah, bfr[(S) & 1][nt], acc[nt], 0, 0, 0); \
      acc[nt] = __builtin_amdgcn_mfma_f32_32x32x16_bf16(al, bfr[(S) & 1][nt], acc[nt], 0, 0, 0); } }

#define FSTEP(S, KV) { \
    if ((S) < 15) LOADB((S) + 1, ((S) + 1) & 1) \
    __builtin_amdgcn_sched_barrier(0); \
    WAITVM(KV); \
    __builtin_amdgcn_sched_barrier(0); \
    __builtin_amdgcn_s_barrier(); \
    if ((S) + 3 <= 15) { FSTG((S) + 3); } \
    __builtin_amdgcn_sched_barrier(0); \
    FCOMP(S) }

  FSTEP(0, 6)  FSTEP(1, 5)  FSTEP(2, 5)  FSTEP(3, 5)
  FSTEP(4, 5)  FSTEP(5, 5)  FSTEP(6, 5)  FSTEP(7, 5)
  FSTEP(8, 5)  FSTEP(9, 5)  FSTEP(10, 5) FSTEP(11, 5)
  FSTEP(12, 5) FSTEP(13, 5) FSTEP(14, 4) FSTEP(15, 0)

  // row sum-of-squares: C/D layout col=lane&31 (=c'), row=(g&3)+8*(g>>2)+4*h
  #pragma unroll
  for (int g = 0; g < 16; g++) {
    float s = acc[0][g] * acc[0][g] + acc[1][g] * acc[1][g]
            + acc[2][g] * acc[2][g] + acc[3][g] * acc[3][g];
    #pragma unroll
    for (int m = 1; m <= 16; m <<= 1) s += __shfl_xor(s, m, 64);  // within 32-half
    if (l31 == 0)
      ssbuf[nh][mt * 32 + (g & 3) + 8 * (g >> 2) + 4 * h] = s;
  }
  __syncthreads();

  float rwv[4];
  #pragma unroll
  for (int nt = 0; nt < 4; nt++)
    rwv[nt] = rms_w[nh * 128 + nt * 32 + l31];

  const int jj  = lane & 7;   // j within octet
  const int icq = l31 >> 3;   // ch octet q

  #pragma unroll
  for (int g = 0; g < 16; g++) {
    const int rg   = (g & 3) + 8 * (g >> 2) + 4 * h;
    const int posg = mt * 32 + rg;
    float ssum = ssbuf[0][posg] + ssbuf[1][posg];
    float sc = rsqrtf(ssum * (1.0f / 256.0f) + 1e-5f);
    if (posg < 56) {
      const int col = posg + 1;
      const size_t rowoff = ((size_t)icq * 64 + col) * 8 + jj;   // octet-major
      #pragma unroll
      for (int nt = 0; nt < 4; nt++) {
        const int cc = nh * 4 + nt;                 // c' = cc*32 + l31
        size_t go = (((size_t)cc * 32 + n) * PROW + (y + 1)) * 2048 + rowoff;
        A[go] = f2bf(acc[nt][g] * sc * rwv[nt]);
      }
    }
  }

  // halo cols 0 and 57..63 of this row (all 4 q-octets)
  {
    const v8s z = {0,0,0,0,0,0,0,0};
    int cc = tid >> 5;
    int s  = tid & 31;
    int q  = s >> 3, cidx = s & 7;
    int col = (cidx == 0) ? 0 : (56 + cidx);       // {0,57,...,63}
    size_t rb = (((size_t)cc * 32 + n) * PROW + (y + 1)) * 2048;
    *(v8s*)(A + rb + ((size_t)q * 64 + col) * 8) = z;
  }
  // halo rows 0 / 57 (full rows, layout-agnostic)
  if (y == 0 || y == 55) {
    const v8s z = {0,0,0,0,0,0,0,0};
    const int r = (y == 0) ? 0 : 57;
    #pragma unroll
    for (int i = 0; i < 8; i++) {
      int c = tid + 256 * i;             // 2048 chunks
      int cc = c >> 8, rem = c & 255;
      size_t go = (((size_t)cc * 32 + n) * PROW + r) * 2048 + rem * 8;
      *(v8s*)(A + go) = z;
    }
  }
#undef FSTG
#undef LOADB
#undef FCOMP
#undef FSTEP
}

// ---------------- kernel 2: W fp32 -> swizzled bf16 (octet-major) ----------------
__global__ __launch_bounds__(256) void wconv_kernel(
    const float* __restrict__ Wf, u16* __restrict__ Wb)
{
  int t = blockIdx.x * 256 + threadIdx.x;
  int kk = t >> 16;
  int cc = (t >> 13) & 7;
  int r  = t & 8191;
  int ocb = r >> 12;
  int q   = (r >> 10) & 3;
  int ocl = (r >> 3) & 127;
  int j   = r & 7;
  int oc = ocb * 128 + ocl;
  int ic = cc * 32 + q * 8 + j;
  int ky = kk / 3, kx = kk - ky * 3;
  float w = Wf[((oc * 256 + ic) * 3 + ky) * 3 + kx];
  Wb[t] = f2bf(w);
}

// ---------------- kernel 3: implicit-GEMM conv ----------------
// A double-buffered in LDS (32 KB); B streamed L2->registers with a
// ky-group software pipeline: two register groups of 12 v8s, group for
// ky+1 (or next cc's ky0) issued before the MFMAs of ky. Top-of-phase
// wait is COUNTED vmcnt(12): drains only the 4 staging DMAs, keeps the
// 12 prefetched B loads in flight. 8 barriers/block, no vmcnt(0) drains.
// 1-D grid with XCD-pair swizzle: the two ocb halves of one (y,n) tile
// sit 8 apart in linear id -> same XCD L2, concurrent -> A fetched once.
__global__ __launch_bounds__(256, 3) void conv_kernel(
    const u16* __restrict__ A, const u16* __restrict__ Wb,
    const float* __restrict__ bias, float* __restrict__ out)
{
  __shared__ __align__(16) u16 As2[2][8192];          // 2 x 16 KB: 4 rows [q4][col64][j8]

  const int tid  = threadIdx.x;
  const int lane = tid & 63;
  const int wv   = tid >> 6;
  const int wm   = wv & 1;          // output row within pair
  const int wn   = wv >> 1;         // oc 64-half
  const int m31  = lane & 31;
  const int kh8  = lane >> 5;       // k-octet selector

  const int bid = blockIdx.x;                 // 0..1791
  const int sg  = bid & 15;
  const int ocb = sg >> 3;
  const int pr  = (bid >> 4) * 8 + (sg & 7);  // 0..895
  const int n   = pr / 28;
  const int yq  = pr - n * 28;
  const int y0  = yq * 2;

  const u16* gA = A + ((size_t)n * PROW + y0) * 2048;

  v16f acc[2][2];
  #pragma unroll
  for (int i = 0; i < 2; i++)
    #pragma unroll
    for (int j = 0; j < 2; j++)
      #pragma unroll
      for (int e = 0; e < 16; e++)
        acc[i][j][e] = 0.0f;

  // B fragment offsets (u16 idx within a (kk,cc,ocb) 4096-elem block)
  int ub[2][2];
  #pragma unroll
  for (int nf = 0; nf < 2; nf++)
    #pragma unroll
    for (int kh = 0; kh < 2; kh++) {
      int ocl = wn * 64 + nf * 32 + m31;      // 0..127
      int q = kh * 2 + kh8;
      ub[nf][kh] = (q * 128 + ocl) * 8;
    }

  v8s bkA[3][2][2], bkB[3][2][2];             // [kx][nf][kh], 12 v8s each

#define STAGE_A(CCV) { const u16* g = gA + (size_t)(CCV) * A_CC_STRIDE + tid * 8; \
    u16* d = &As2[(CCV) & 1][0] + tid * 8; \
    _Pragma("unroll") for (int k = 0; k < 4; k++) gl2lds16(g + k * 2048, d + k * 2048); }

#define LOADBK(DST, CCV, KYV) { _Pragma("unroll") for (int kx = 0; kx < 3; kx++) { \
    const u16* bt = Wb + (size_t)(((((KYV) * 3 + kx) * 8 + (CCV)) * 8192) + ocb * 4096); \
    _Pragma("unroll") for (int nf = 0; nf < 2; nf++) \
      _Pragma("unroll") for (int kh = 0; kh < 2; kh++) \
        DST[kx][nf][kh] = *(const v8s*)(bt + ub[nf][kh]); } }

#define KYBLK(CC, KY, BUSE) { \
    const u16* asb = &As2[(CC) & 1][0]; \
    _Pragma("unroll") for (int kx = 0; kx < 3; kx++) { \
      v8s af[2][2]; \
      _Pragma("unroll") for (int mf = 0; mf < 2; mf++) \
        _Pragma("unroll") for (int kh = 0; kh < 2; kh++) { \
          int col = mf * 32 + m31 + kx; \
          col = col > 63 ? 63 : col; \
          int q = kh * 2 + kh8; \
          af[mf][kh] = *(const v8s*)(asb + ((wm + (KY)) * 4 + q) * 512 + col * 8); } \
      _Pragma("unroll") for (int mf = 0; mf < 2; mf++) \
        _Pragma("unroll") for (int nf = 0; nf < 2; nf++) { \
          acc[mf][nf] = __builtin_amdgcn_mfma_f32_32x32x16_bf16(af[mf][0], BUSE[kx][nf][0], acc[mf][nf], 0, 0, 0); \
          acc[mf][nf] = __builtin_amdgcn_mfma_f32_32x32x16_bf16(af[mf][1], BUSE[kx][nf][1], acc[mf][nf], 0, 0, 0); } } }

  // P enters each cc holding (cc, ky0); Q is the scratch group.
#define CONV_CC(CC, P, Q) { \
    WAITVM(12); \
    __builtin_amdgcn_s_barrier(); \
    if ((CC) < 7) STAGE_A((CC) + 1) \
    __builtin_amdgcn_sched_barrier(0); \
    LOADBK(Q, CC, 1) \
    KYBLK(CC, 0, P) \
    LOADBK(P, CC, 2) \
    KYBLK(CC, 1, Q) \
    if ((CC) < 7) LOADBK(Q, (CC) + 1, 0) \
    KYBLK(CC, 2, P) }

  // prologue: stage cc=0, prefetch (0, ky0) into bkA
  STAGE_A(0)
  LOADBK(bkA, 0, 0)

  CONV_CC(0, bkA, bkB) CONV_CC(1, bkB, bkA)
  CONV_CC(2, bkA, bkB) CONV_CC(3, bkB, bkA)
  CONV_CC(4, bkA, bkB) CONV_CC(5, bkB, bkA)
  CONV_CC(6, bkA, bkB) CONV_CC(7, bkB, bkA)

#undef STAGE_A
#undef LOADBK
#undef KYBLK
#undef CONV_CC

  // epilogue: C/D 32x32: col(lane&31)=oc, row = (reg&3) + 8*(reg>>2) + 4*(lane>>5) = x
  const int yrow = y0 + wm;
  #pragma unroll
  for (int nf = 0; nf < 2; nf++) {
    const int oc = ocb * 128 + wn * 64 + nf * 32 + m31;
    const float bb = bias[oc];
    float* orow = out + ((size_t)(n * 256 + oc) * 56 + yrow) * 56;
    #pragma unroll
    for (int mf = 0; mf < 2; mf++) {
      #pragma unroll
      for (int g = 0; g < 4; g++) {
        const int x0 = mf * 32 + 8 * g + 4 * kh8;
        if (x0 < 56) {
          v4f val = { acc[mf][nf][4*g+0] + bb, acc[mf][nf][4*g+1] + bb,
                      acc[mf][nf][4*g+2] + bb, acc[mf][nf][4*g+3] + bb };
          *(v4f*)(orow + x0) = val;
        }
      }
    }
  }
}

extern "C" void kernel_launch(void* const* d_in, const int* in_sizes, int n_in,
                              void* d_out, int out_size, void* d_ws, size_t ws_size,
                              hipStream_t stream)
{
  const float* x     = (const float*)d_in[0];
  const float* Wf    = (const float*)d_in[1];
  const float* bias  = (const float*)d_in[2];
  const float* rms_w = (const float*)d_in[3];
  float* out = (float*)d_out;

  if (ws_size < A_BYTES + WB_ELEMS * 2) return;

  u16* Abf = (u16*)d_ws;
  u16* Wb  = (u16*)((char*)d_ws + A_BYTES);

  fwht_kernel<<<dim3(56, 32), 256, 0, stream>>>(x, rms_w, Abf);
  wconv_kernel<<<dim3((int)(WB_ELEMS / 256)), 256, 0, stream>>>(Wf, Wb);
  conv_kernel<<<dim3(1792), 256, 0, stream>>>(Abf, Wb, bias, out);
}